// Round 17
// baseline (181.519 us; speedup 1.0000x reference)
//
#include <hip/hip_runtime.h>
#include <hip/hip_bf16.h>

typedef unsigned short u16;
typedef unsigned char u8;
typedef float f32x4 __attribute__((ext_vector_type(4)));
typedef int i32x4 __attribute__((ext_vector_type(4)));

#define NTOK 32768   // B*S = 8*4096
#define DIM  512
#define KC   4096

__device__ __forceinline__ void gload_lds16(const void* g, void* l) {
  __builtin_amdgcn_global_load_lds(
      (__attribute__((address_space(1))) void*)g,
      (__attribute__((address_space(3))) void*)l,
      16, 0, 0);
}

__device__ __forceinline__ unsigned pk4(float a, float b, float c, float d, float inv) {
  int b0 = __float2int_rn(a * inv), b1 = __float2int_rn(b * inv);
  int b2 = __float2int_rn(c * inv), b3 = __float2int_rn(d * inv);
  return (unsigned)(b0 & 255) | ((unsigned)(b1 & 255) << 8) |
         ((unsigned)(b2 & 255) << 16) | ((unsigned)(b3 & 255) << 24);
}

// swizzled destination for one lane's 8B block within a row:
// 16B slot s lives at s ^ ((row>>1)&3)  -> 2 lanes/bank on b128 reads (free)
__device__ __forceinline__ size_t swz_dst(int row, int lane) {
  int chunk = lane >> 3;          // 64B K-chunk 0..7
  int s8    = lane & 7;           // 8B block in chunk
  int h     = (row >> 1) & 3;
  return (size_t)row * DIM + chunk * 64 + ((((s8 >> 1) ^ h) << 4) | ((s8 & 1) << 3));
}

// ---- prep: X fp32 -> i8 per-token symmetric quant (swizzled layout) -------
__global__ void cvt_x_i8(const float* __restrict__ in, u8* __restrict__ q,
                         float* __restrict__ xs) {
  int row  = blockIdx.x * 4 + (threadIdx.x >> 6);
  int lane = threadIdx.x & 63;
  const float* src = in + (size_t)row * DIM + lane * 8;
  float4 a = *reinterpret_cast<const float4*>(src);
  float4 b = *reinterpret_cast<const float4*>(src + 4);
  float m = fmaxf(fmaxf(fmaxf(fabsf(a.x), fabsf(a.y)), fmaxf(fabsf(a.z), fabsf(a.w))),
                  fmaxf(fmaxf(fabsf(b.x), fabsf(b.y)), fmaxf(fabsf(b.z), fabsf(b.w))));
#pragma unroll
  for (int s = 1; s < 64; s <<= 1) m = fmaxf(m, __shfl_xor(m, s, 64));
  float inv = 127.0f / fmaxf(m, 1e-20f);
  uint2 w2;
  w2.x = pk4(a.x, a.y, a.z, a.w, inv);
  w2.y = pk4(b.x, b.y, b.z, b.w, inv);
  *reinterpret_cast<uint2*>(q + swz_dst(row, lane)) = w2;
  if (lane == 0) xs[row] = m * (1.0f / 127.0f);
}

// codebook -> i8 per-code quant (swizzled) + exact fp32 norm; cs2 = 2*maxabs/127
__global__ void cvt_cb_i8(const float* __restrict__ cb, u8* __restrict__ cq,
                          float* __restrict__ cnorm, float* __restrict__ cs2) {
  int row  = blockIdx.x * 4 + (threadIdx.x >> 6);
  int lane = threadIdx.x & 63;
  const float* src = cb + (size_t)row * DIM + lane * 8;
  float4 a = *reinterpret_cast<const float4*>(src);
  float4 b = *reinterpret_cast<const float4*>(src + 4);
  float m = fmaxf(fmaxf(fmaxf(fabsf(a.x), fabsf(a.y)), fmaxf(fabsf(a.z), fabsf(a.w))),
                  fmaxf(fmaxf(fabsf(b.x), fabsf(b.y)), fmaxf(fabsf(b.z), fabsf(b.w))));
  float s = a.x*a.x + a.y*a.y + a.z*a.z + a.w*a.w
          + b.x*b.x + b.y*b.y + b.z*b.z + b.w*b.w;
#pragma unroll
  for (int sh = 1; sh < 64; sh <<= 1) {
    m = fmaxf(m, __shfl_xor(m, sh, 64));
    s += __shfl_xor(s, sh, 64);
  }
  float inv = 127.0f / fmaxf(m, 1e-20f);
  uint2 w2;
  w2.x = pk4(a.x, a.y, a.z, a.w, inv);
  w2.y = pk4(b.x, b.y, b.z, b.w, inv);
  *reinterpret_cast<uint2*>(cq + swz_dst(row, lane)) = w2;
  if (lane == 0) { cnorm[row] = s; cs2[row] = 2.0f * m * (1.0f / 127.0f); }
}

// gate W -> i8 per-row quant (swizzled); ws[row] = maxabs/127
__global__ void cvt_w_i8(const float* __restrict__ w, u8* __restrict__ wq,
                         float* __restrict__ ws) {
  int row  = blockIdx.x * 4 + (threadIdx.x >> 6);
  int lane = threadIdx.x & 63;
  const float* src = w + (size_t)row * DIM + lane * 8;
  float4 a = *reinterpret_cast<const float4*>(src);
  float4 b = *reinterpret_cast<const float4*>(src + 4);
  float m = fmaxf(fmaxf(fmaxf(fabsf(a.x), fabsf(a.y)), fmaxf(fabsf(a.z), fabsf(a.w))),
                  fmaxf(fmaxf(fabsf(b.x), fabsf(b.y)), fmaxf(fabsf(b.z), fabsf(b.w))));
#pragma unroll
  for (int s = 1; s < 64; s <<= 1) m = fmaxf(m, __shfl_xor(m, s, 64));
  float inv = 127.0f / fmaxf(m, 1e-20f);
  uint2 w2;
  w2.x = pk4(a.x, a.y, a.z, a.w, inv);
  w2.y = pk4(b.x, b.y, b.z, b.w, inv);
  *reinterpret_cast<uint2*>(wq + swz_dst(row, lane)) = w2;
  if (lane == 0) ws[row] = m * (1.0f / 127.0f);
}

// --------------- argmin GEMM (i8): score = cnorm - xs*cs2*idot -------------
// X-RESIDENT restructure: each block holds its full 128x512B X tile in LDS
// (staged once, 64 KiB) and streams 16 code tiles x 8 K-chunks through a
// 2-buffer ring (R16-verified skeleton per stage). Swapped MFMA (A=codes,
// B=tokens) keeps argmin lane-local; running best folds at each code-tile
// boundary in registers. X staging traffic drops 537->34 MB; partials 32->2.
__global__ __launch_bounds__(256)
void argmin_i8(const u8* __restrict__ Xq, const u8* __restrict__ Cq,
               const float* __restrict__ cnorm, const float* __restrict__ cs2,
               const float* __restrict__ xs,
               float* __restrict__ pval, int* __restrict__ pidx) {
  __shared__ __align__(16) u8 Xs[8 * 128 * 64];   // 64 KiB [kchunk][row][64B]
  __shared__ __align__(16) u8 Cs[2][128 * 64];    // 16 KiB ring

  const int tid  = threadIdx.x;
  const int lane = tid & 63;
  const int wid  = tid >> 6;          // 0..3
  const int wr   = wid >> 1;          // 0..1 (CODE half within tile)
  const int wc   = wid & 1;           // 0..1 (TOKEN half)
  const int bm   = blockIdx.x;        // 0..255 token tiles (128 each)
  const int bnH  = blockIdx.y;        // 0..1  code halves (2048 each)
  const int l15  = lane & 15, l4 = lane >> 4;

  const u8* Xg = Xq + (size_t)(bm * 128) * DIM;
  const u8* Cg = Cq + (size_t)(bnH * 2048) * DIM;

  // stage whole X tile once: 16 gload_lds16 / thread
  auto stageX = [&]() {
#pragma unroll
    for (int t = 0; t < 8; t++)
#pragma unroll
      for (int p = 0; p < 2; p++) {
        int row = p * 64 + wid * 16 + (lane >> 2);
        gload_lds16(Xg + (size_t)row * DIM + t * 64 + (lane & 3) * 16,
                    (void*)(Xs + t * 8192 + (p * 64 + wid * 16) * 64));
      }
  };
  // stage one C chunk (code tile g = s>>3, K-chunk t = s&7): 2 gloads/thread
  auto stageC = [&](int buf, int s) {
    int g = s >> 3, t = s & 7;
    const u8* base = Cg + (size_t)(g * 128) * DIM + t * 64;
#pragma unroll
    for (int p = 0; p < 2; p++) {
      int row = p * 64 + wid * 16 + (lane >> 2);
      gload_lds16(base + (size_t)row * DIM + (lane & 3) * 16,
                  (void*)(Cs[buf] + (p * 64 + wid * 16) * 64));
    }
  };
  auto rd16 = [&](const u8* base, int row) -> i32x4 {
    return *reinterpret_cast<const i32x4*>(
        base + row * 64 + ((l4 ^ ((row >> 1) & 3)) << 4));
  };

  float xsv[4];
  float best[4];
  int   bi[4];
#pragma unroll
  for (int ni = 0; ni < 4; ni++) {
    xsv[ni]  = xs[bm * 128 + wc * 64 + ni * 16 + l15];
    best[ni] = 1e30f;
    bi[ni]   = 0;
  }

  i32x4 acc[4][4];   // [mi=code blk][ni=token blk]
#pragma unroll
  for (int i = 0; i < 4; i++)
#pragma unroll
    for (int j = 0; j < 4; j++)
#pragma unroll
      for (int r = 0; r < 4; r++) acc[i][j][r] = 0;

  stageX();
  stageC(0, 0);
  stageC(1, 1);
  asm volatile("s_waitcnt vmcnt(2)" ::: "memory");   // X + C0 landed
  __builtin_amdgcn_s_barrier();
  asm volatile("" ::: "memory");

  const int NS = 128;   // 16 code tiles x 8 K-chunks
  for (int s = 0; s < NS; ++s) {
    const u8* Ct = Cs[s & 1];
    const u8* Xt = Xs + (s & 7) * 8192;
    i32x4 xfr[4];
#pragma unroll
    for (int ni = 0; ni < 4; ni++) xfr[ni] = rd16(Xt, wc * 64 + ni * 16 + l15);
#pragma unroll
    for (int mi = 0; mi < 4; mi++) {
      i32x4 cf = rd16(Ct, wr * 64 + mi * 16 + l15);
      __builtin_amdgcn_s_setprio(1);
#pragma unroll
      for (int ni = 0; ni < 4; ni++)
        acc[mi][ni] = __builtin_amdgcn_mfma_i32_16x16x64_i8(
            cf, xfr[ni], acc[mi][ni], 0, 0, 0);   // A=codes, B=tokens
      __builtin_amdgcn_s_setprio(0);
    }

    if ((s & 7) == 7) {          // code-tile boundary: fold acc into best
      int gbase = bnH * 2048 + (s >> 3) * 128 + wr * 64;
      float cn[4][4], c2q[4][4];
#pragma unroll
      for (int mi = 0; mi < 4; mi++)
#pragma unroll
        for (int r = 0; r < 4; r++) {
          int code = gbase + mi * 16 + l4 * 4 + r;
          cn[mi][r]  = cnorm[code];
          c2q[mi][r] = cs2[code];
        }
#pragma unroll
      for (int ni = 0; ni < 4; ni++)
#pragma unroll
        for (int mi = 0; mi < 4; mi++)
#pragma unroll
          for (int r = 0; r < 4; r++) {
            float v = fmaf(-xsv[ni] * c2q[mi][r], (float)acc[mi][ni][r], cn[mi][r]);
            if (v < best[ni]) { best[ni] = v; bi[ni] = gbase + mi * 16 + l4 * 4 + r; }
          }
#pragma unroll
      for (int i = 0; i < 4; i++)
#pragma unroll
        for (int j = 0; j < 4; j++)
#pragma unroll
          for (int r = 0; r < 4; r++) acc[i][j][r] = 0;
    }

    asm volatile("" ::: "memory");
    __builtin_amdgcn_s_barrier();          // all waves done reading Cs[s&1]
    asm volatile("" ::: "memory");
    if (s + 2 < NS) {
      stageC(s & 1, s + 2);                // refill freed buffer
      asm volatile("s_waitcnt vmcnt(2)" ::: "memory");   // C(s+1) landed
      __builtin_amdgcn_s_barrier();
      asm volatile("" ::: "memory");
    } else if (s == NS - 2) {
      asm volatile("s_waitcnt vmcnt(0)" ::: "memory");
      __builtin_amdgcn_s_barrier();
      asm volatile("" ::: "memory");
    }
  }

  // ---- final: 2 shuffle rounds over l4, cross-wr combine via LDS ----------
  float* rv = (float*)Cs[0];   // [2][128]
  int*   ri = (int*)Cs[1];
  __syncthreads();

#pragma unroll
  for (int ni = 0; ni < 4; ni++) {
    float b = best[ni];
    int   c = bi[ni];
#pragma unroll
    for (int m = 16; m < 64; m <<= 1) {
      float ov = __shfl_xor(b, m, 64);
      int   oi = __shfl_xor(c, m, 64);
      if (ov < b) { b = ov; c = oi; }
    }
    if (l4 == 0) {
      int tl = wc * 64 + ni * 16 + l15;
      rv[wr * 128 + tl] = b;
      ri[wr * 128 + tl] = c;
    }
  }
  __syncthreads();
  if (tid < 128) {
    float bv = rv[tid];
    int   bb = ri[tid];
    float v1 = rv[128 + tid];
    if (v1 < bv) { bv = v1; bb = ri[128 + tid]; }
    size_t g = (size_t)bnH * NTOK + bm * 128 + tid;
    pval[g] = bv;
    pidx[g] = bb;
  }
}

__global__ void argmin_reduce(const float* __restrict__ pval, const int* __restrict__ pidx,
                              int* __restrict__ idx) {
  int t = blockIdx.x * 256 + threadIdx.x;   // 0..32767
  float v0 = pval[t], v1 = pval[(size_t)NTOK + t];
  int   i0 = pidx[t], i1 = pidx[(size_t)NTOK + t];
  idx[t] = (v1 < v0) ? i1 : i0;
}

// -------- gate GEMM (i8, R16-verified) + fused epilogue + loss -------------
__global__ __launch_bounds__(512, 4)
void gate_i8(const u8* __restrict__ Xq, const u8* __restrict__ Wq,
             const float* __restrict__ X, const float* __restrict__ Cf,
             const float* __restrict__ gb, const float* __restrict__ xs,
             const float* __restrict__ ws, const int* __restrict__ idx,
             float* __restrict__ out, float* __restrict__ blockSum) {
  __shared__ __align__(16) u8 As[2][128 * 64];
  __shared__ __align__(16) u8 Bs[2][256 * 64];
  __shared__ float bsum[8];

  const int tid  = threadIdx.x;
  const int lane = tid & 63;
  const int wid  = tid >> 6;          // 0..7
  const int wr   = wid >> 2;          // 0..1
  const int wc   = wid & 3;           // 0..3
  const int bm   = blockIdx.x;        // 0..255 token tiles
  const int bn   = blockIdx.y;        // 0..1   col tiles (256 each)
  const int l15  = lane & 15, l4 = lane >> 4;

  const u8* Xg = Xq + (size_t)(bm * 128) * DIM;
  const u8* Wg = Wq + (size_t)(bn * 256) * DIM;

  auto stage = [&](int buf, int kt) {
    int kk = kt * 64;
    {
      int row = wid * 16 + (lane >> 2);
      gload_lds16(Xg + (size_t)row * DIM + kk + (lane & 3) * 16,
                  (void*)(As[buf] + wid * 1024));
    }
#pragma unroll
    for (int p = 0; p < 2; p++) {
      int row = p * 128 + wid * 16 + (lane >> 2);
      gload_lds16(Wg + (size_t)row * DIM + kk + (lane & 3) * 16,
                  (void*)(Bs[buf] + p * 8192 + wid * 1024));
    }
  };

  auto rd16 = [&](const u8* base, int row) -> i32x4 {
    return *reinterpret_cast<const i32x4*>(
        base + row * 64 + ((l4 ^ ((row >> 1) & 3)) << 4));
  };

  i32x4 acc[4][4];
#pragma unroll
  for (int i = 0; i < 4; i++)
#pragma unroll
    for (int j = 0; j < 4; j++)
#pragma unroll
      for (int r = 0; r < 4; r++) acc[i][j][r] = 0;

  stage(0, 0);
  stage(1, 1);
  asm volatile("s_waitcnt vmcnt(3)" ::: "memory");
  __builtin_amdgcn_s_barrier();
  asm volatile("" ::: "memory");

  for (int t = 0; t < 8; ++t) {
    const u8* A  = As[t & 1];
    const u8* Bt = Bs[t & 1];
    i32x4 bfr[4];
#pragma unroll
    for (int ni = 0; ni < 4; ni++) bfr[ni] = rd16(Bt, wc * 64 + ni * 16 + l15);
#pragma unroll
    for (int mi = 0; mi < 4; mi++) {
      i32x4 af = rd16(A, wr * 64 + mi * 16 + l15);
      __builtin_amdgcn_s_setprio(1);
#pragma unroll
      for (int ni = 0; ni < 4; ni++)
        acc[mi][ni] = __builtin_amdgcn_mfma_i32_16x16x64_i8(
            af, bfr[ni], acc[mi][ni], 0, 0, 0);
      __builtin_amdgcn_s_setprio(0);
    }

    asm volatile("" ::: "memory");
    __builtin_amdgcn_s_barrier();
    asm volatile("" ::: "memory");
    if (t + 2 < 8) {
      stage(t & 1, t + 2);
      asm volatile("s_waitcnt vmcnt(3)" ::: "memory");
      __builtin_amdgcn_s_barrier();
      asm volatile("" ::: "memory");
    } else if (t < 7) {
      asm volatile("s_waitcnt vmcnt(0)" ::: "memory");
      __builtin_amdgcn_s_barrier();
      asm volatile("" ::: "memory");
    }
  }

  // epilogue: gate = sigmoid(xs*ws*idot + b), out = x + c[idx]*gate, loss
  float wsv[4], gbv[4];
  int   cl[4];
#pragma unroll
  for (int ni = 0; ni < 4; ni++) {
    cl[ni] = bn * 256 + wc * 64 + ni * 16 + l15;
    wsv[ni] = ws[cl[ni]];
    gbv[ni] = gb[cl[ni]];
  }
  float lsum = 0.f;
#pragma unroll
  for (int mi = 0; mi < 4; mi++) {
#pragma unroll
    for (int r = 0; r < 4; r++) {
      int token = bm * 128 + wr * 64 + mi * 16 + l4 * 4 + r;
      int code = idx[token];
      float xsv = xs[token];
#pragma unroll
      for (int ni = 0; ni < 4; ni++) {
        int col = cl[ni];
        float logit = xsv * wsv[ni] * (float)acc[mi][ni][r] + gbv[ni];
        float g = 1.0f / (1.0f + __expf(-logit));
        float q = Cf[(size_t)code * DIM + col];
        float xx = X[(size_t)token * DIM + col];
        out[(size_t)token * DIM + col] = xx + q * g;
        float d = q - xx;
        lsum += d * d;
      }
    }
  }
#pragma unroll
  for (int m = 1; m < 64; m <<= 1) lsum += __shfl_xor(lsum, m, 64);
  if (lane == 0) bsum[wid] = lsum;
  __syncthreads();
  if (tid == 0) {
    float s = 0.f;
#pragma unroll
    for (int i = 0; i < 8; i++) s += bsum[i];
    blockSum[blockIdx.y * gridDim.x + blockIdx.x] = s;
  }
}

__global__ void finalize(const float* __restrict__ blockSum, float* __restrict__ out_loss) {
  int t = threadIdx.x;  // 256 threads, 512 partials
  float s = blockSum[t * 2] + blockSum[t * 2 + 1];
#pragma unroll
  for (int m = 1; m < 64; m <<= 1) s += __shfl_xor(s, m, 64);
  __shared__ float w4[4];
  if ((t & 63) == 0) w4[t >> 6] = s;
  __syncthreads();
  if (t == 0) {
    float tot = w4[0] + w4[1] + w4[2] + w4[3];
    out_loss[0] = 1.25f * tot / 16777216.0f;   // N*D = 32768*512
  }
}

extern "C" void kernel_launch(void* const* d_in, const int* in_sizes, int n_in,
                              void* d_out, int out_size, void* d_ws, size_t ws_size,
                              hipStream_t stream) {
  const float* X  = (const float*)d_in[0];   // [32768, 512]
  const float* CB = (const float*)d_in[1];   // [4096, 512]
  const float* GW = (const float*)d_in[2];   // [512, 512]
  const float* GB = (const float*)d_in[3];   // [512]
  float* out = (float*)d_out;                // [32768*512] output + [1] loss

  char* w = (char*)d_ws;
  size_t off = 0;
  auto alloc = [&](size_t bytes) -> void* {
    void* p = w + off;
    off = (off + bytes + 255) & ~(size_t)255;
    return p;
  };
  u8*    Xq    = (u8*) alloc((size_t)NTOK * DIM);       // 16.8 MB (i8, swizzled)
  u8*    Cq    = (u8*) alloc((size_t)KC * DIM);         // 2.1 MB
  u8*    Wq    = (u8*) alloc((size_t)DIM * DIM);        // 0.25 MB
  float* xsc   = (float*)alloc((size_t)NTOK * 4);       // per-token scale
  float* cnorm = (float*)alloc((size_t)KC * 4);
  float* cs2   = (float*)alloc((size_t)KC * 4);
  float* wsc   = (float*)alloc((size_t)DIM * 4);
  float* pval  = (float*)alloc((size_t)2 * NTOK * 4);   // 0.26 MB
  int*   pidx  = (int*)alloc((size_t)2 * NTOK * 4);     // 0.26 MB
  int*   idx   = (int*)alloc((size_t)NTOK * 4);
  float* bsums = (float*)alloc((size_t)512 * 4);

  cvt_x_i8<<<8192, 256, 0, stream>>>(X, Xq, xsc);
  cvt_cb_i8<<<1024, 256, 0, stream>>>(CB, Cq, cnorm, cs2);
  cvt_w_i8<<<128, 256, 0, stream>>>(GW, Wq, wsc);
  argmin_i8<<<dim3(256, 2), 256, 0, stream>>>(Xq, Cq, cnorm, cs2, xsc, pval, pidx);
  argmin_reduce<<<128, 256, 0, stream>>>(pval, pidx, idx);
  gate_i8<<<dim3(256, 2), 512, 0, stream>>>(Xq, Wq, X, CB, GB, xsc, wsc, idx, out, bsums);
  finalize<<<1, 256, 0, stream>>>(bsums, out + (size_t)NTOK * DIM);
}

// Round 18
// 169.274 us; speedup vs baseline: 1.0723x; 1.0723x over previous
//
#include <hip/hip_runtime.h>
#include <hip/hip_bf16.h>

typedef unsigned short u16;
typedef unsigned char u8;
typedef float f32x4 __attribute__((ext_vector_type(4)));
typedef int i32x4 __attribute__((ext_vector_type(4)));

#define NTOK 32768   // B*S = 8*4096
#define DIM  512
#define KC   4096

__device__ __forceinline__ void gload_lds16(const void* g, void* l) {
  __builtin_amdgcn_global_load_lds(
      (__attribute__((address_space(1))) void*)g,
      (__attribute__((address_space(3))) void*)l,
      16, 0, 0);
}

__device__ __forceinline__ unsigned pk4(float a, float b, float c, float d, float inv) {
  int b0 = __float2int_rn(a * inv), b1 = __float2int_rn(b * inv);
  int b2 = __float2int_rn(c * inv), b3 = __float2int_rn(d * inv);
  return (unsigned)(b0 & 255) | ((unsigned)(b1 & 255) << 8) |
         ((unsigned)(b2 & 255) << 16) | ((unsigned)(b3 & 255) << 24);
}

// swizzled destination for one lane's 8B block within a row:
// 16B slot s lives at s ^ ((row>>1)&3)  -> 2 lanes/bank on b128 reads (free)
__device__ __forceinline__ size_t swz_dst(int row, int lane) {
  int chunk = lane >> 3;          // 64B K-chunk 0..7
  int s8    = lane & 7;           // 8B block in chunk
  int h     = (row >> 1) & 3;
  return (size_t)row * DIM + chunk * 64 + ((((s8 >> 1) ^ h) << 4) | ((s8 & 1) << 3));
}

// ---- prep: X fp32 -> i8 per-token symmetric quant (swizzled layout) -------
__global__ void cvt_x_i8(const float* __restrict__ in, u8* __restrict__ q,
                         float* __restrict__ xs) {
  int row  = blockIdx.x * 4 + (threadIdx.x >> 6);
  int lane = threadIdx.x & 63;
  const float* src = in + (size_t)row * DIM + lane * 8;
  float4 a = *reinterpret_cast<const float4*>(src);
  float4 b = *reinterpret_cast<const float4*>(src + 4);
  float m = fmaxf(fmaxf(fmaxf(fabsf(a.x), fabsf(a.y)), fmaxf(fabsf(a.z), fabsf(a.w))),
                  fmaxf(fmaxf(fabsf(b.x), fabsf(b.y)), fmaxf(fabsf(b.z), fabsf(b.w))));
#pragma unroll
  for (int s = 1; s < 64; s <<= 1) m = fmaxf(m, __shfl_xor(m, s, 64));
  float inv = 127.0f / fmaxf(m, 1e-20f);
  uint2 w2;
  w2.x = pk4(a.x, a.y, a.z, a.w, inv);
  w2.y = pk4(b.x, b.y, b.z, b.w, inv);
  *reinterpret_cast<uint2*>(q + swz_dst(row, lane)) = w2;
  if (lane == 0) xs[row] = m * (1.0f / 127.0f);
}

// codebook -> i8 per-code quant (swizzled) + exact fp32 norm; cs2 = 2*maxabs/127
__global__ void cvt_cb_i8(const float* __restrict__ cb, u8* __restrict__ cq,
                          float* __restrict__ cnorm, float* __restrict__ cs2) {
  int row  = blockIdx.x * 4 + (threadIdx.x >> 6);
  int lane = threadIdx.x & 63;
  const float* src = cb + (size_t)row * DIM + lane * 8;
  float4 a = *reinterpret_cast<const float4*>(src);
  float4 b = *reinterpret_cast<const float4*>(src + 4);
  float m = fmaxf(fmaxf(fmaxf(fabsf(a.x), fabsf(a.y)), fmaxf(fabsf(a.z), fabsf(a.w))),
                  fmaxf(fmaxf(fabsf(b.x), fabsf(b.y)), fmaxf(fabsf(b.z), fabsf(b.w))));
  float s = a.x*a.x + a.y*a.y + a.z*a.z + a.w*a.w
          + b.x*b.x + b.y*b.y + b.z*b.z + b.w*b.w;
#pragma unroll
  for (int sh = 1; sh < 64; sh <<= 1) {
    m = fmaxf(m, __shfl_xor(m, sh, 64));
    s += __shfl_xor(s, sh, 64);
  }
  float inv = 127.0f / fmaxf(m, 1e-20f);
  uint2 w2;
  w2.x = pk4(a.x, a.y, a.z, a.w, inv);
  w2.y = pk4(b.x, b.y, b.z, b.w, inv);
  *reinterpret_cast<uint2*>(cq + swz_dst(row, lane)) = w2;
  if (lane == 0) { cnorm[row] = s; cs2[row] = 2.0f * m * (1.0f / 127.0f); }
}

// gate W -> i8 per-row quant (swizzled); ws[row] = maxabs/127
__global__ void cvt_w_i8(const float* __restrict__ w, u8* __restrict__ wq,
                         float* __restrict__ ws) {
  int row  = blockIdx.x * 4 + (threadIdx.x >> 6);
  int lane = threadIdx.x & 63;
  const float* src = w + (size_t)row * DIM + lane * 8;
  float4 a = *reinterpret_cast<const float4*>(src);
  float4 b = *reinterpret_cast<const float4*>(src + 4);
  float m = fmaxf(fmaxf(fmaxf(fabsf(a.x), fabsf(a.y)), fmaxf(fabsf(a.z), fabsf(a.w))),
                  fmaxf(fmaxf(fabsf(b.x), fabsf(b.y)), fmaxf(fabsf(b.z), fabsf(b.w))));
#pragma unroll
  for (int s = 1; s < 64; s <<= 1) m = fmaxf(m, __shfl_xor(m, s, 64));
  float inv = 127.0f / fmaxf(m, 1e-20f);
  uint2 w2;
  w2.x = pk4(a.x, a.y, a.z, a.w, inv);
  w2.y = pk4(b.x, b.y, b.z, b.w, inv);
  *reinterpret_cast<uint2*>(wq + swz_dst(row, lane)) = w2;
  if (lane == 0) ws[row] = m * (1.0f / 127.0f);
}

// --------------- argmin GEMM (i8): score = cnorm - xs*cs2*idot -------------
// R16-verified best: 128x128, BK=64, 4 waves, 2-buf counted vmcnt(4), SWAPPED
// MFMA operands (A=codes, B=tokens) => lane-local argmin, 2 shuffle rounds.
__global__ __launch_bounds__(256)
void argmin_i8(const u8* __restrict__ Xq, const u8* __restrict__ Cq,
               const float* __restrict__ cnorm, const float* __restrict__ cs2,
               const float* __restrict__ xs,
               float* __restrict__ pval, int* __restrict__ pidx) {
  __shared__ __align__(16) u8 As[2][128 * 64];   // X tile, 8 KiB each
  __shared__ __align__(16) u8 Bs[2][128 * 64];   // C tile, 8 KiB each (32 KiB)

  const int tid  = threadIdx.x;
  const int lane = tid & 63;
  const int wid  = tid >> 6;          // 0..3
  const int wr   = wid >> 1;          // 0..1 (CODE half: 64 codes)
  const int wc   = wid & 1;           // 0..1 (TOKEN half: 64 tokens)
  const int bm   = blockIdx.x;        // 0..255 token tiles (128 each)
  const int bn   = blockIdx.y;        // 0..31  code tiles (128 each)
  const int l15  = lane & 15, l4 = lane >> 4;

  const u8* Xg = Xq + (size_t)(bm * 128) * DIM;
  const u8* Cg = Cq + (size_t)(bn * 128) * DIM;

  auto stage = [&](int buf, int kt) {
    int kk = kt * 64;
#pragma unroll
    for (int p = 0; p < 2; p++) {
      int row = p * 64 + wid * 16 + (lane >> 2);   // 0..127
      gload_lds16(Xg + (size_t)row * DIM + kk + (lane & 3) * 16,
                  (void*)(As[buf] + (p * 64 + wid * 16) * 64));
      gload_lds16(Cg + (size_t)row * DIM + kk + (lane & 3) * 16,
                  (void*)(Bs[buf] + (p * 64 + wid * 16) * 64));
    }
  };

  // swizzled b128 fragment read: logical slot l4 -> phys l4 ^ ((row>>1)&3)
  auto rd16 = [&](const u8* base, int row) -> i32x4 {
    return *reinterpret_cast<const i32x4*>(
        base + row * 64 + ((l4 ^ ((row >> 1) & 3)) << 4));
  };

  i32x4 acc[4][4];   // [mi=code blk][ni=token blk]
#pragma unroll
  for (int i = 0; i < 4; i++)
#pragma unroll
    for (int j = 0; j < 4; j++)
#pragma unroll
      for (int r = 0; r < 4; r++) acc[i][j][r] = 0;

  stage(0, 0);
  stage(1, 1);
  asm volatile("s_waitcnt vmcnt(4)" ::: "memory");   // tile0's 4 landed
  __builtin_amdgcn_s_barrier();
  asm volatile("" ::: "memory");

  for (int t = 0; t < 8; ++t) {
    const u8* Xt = As[t & 1];
    const u8* Ct = Bs[t & 1];
    i32x4 xfr[4];
#pragma unroll
    for (int ni = 0; ni < 4; ni++) xfr[ni] = rd16(Xt, wc * 64 + ni * 16 + l15);
#pragma unroll
    for (int mi = 0; mi < 4; mi++) {
      i32x4 cf = rd16(Ct, wr * 64 + mi * 16 + l15);
      __builtin_amdgcn_s_setprio(1);
#pragma unroll
      for (int ni = 0; ni < 4; ni++)
        acc[mi][ni] = __builtin_amdgcn_mfma_i32_16x16x64_i8(
            cf, xfr[ni], acc[mi][ni], 0, 0, 0);   // A=codes, B=tokens
      __builtin_amdgcn_s_setprio(0);
    }

    asm volatile("" ::: "memory");
    __builtin_amdgcn_s_barrier();
    asm volatile("" ::: "memory");
    if (t + 2 < 8) {
      stage(t & 1, t + 2);
      asm volatile("s_waitcnt vmcnt(4)" ::: "memory");
      __builtin_amdgcn_s_barrier();
      asm volatile("" ::: "memory");
    } else if (t < 7) {
      asm volatile("s_waitcnt vmcnt(0)" ::: "memory");
      __builtin_amdgcn_s_barrier();
      asm volatile("" ::: "memory");
    }
  }

  // ---- epilogue: lane-local argmin over 16 codes, 2 shuffle rounds --------
  float cn[4][4], c2q[4][4];
#pragma unroll
  for (int mi = 0; mi < 4; mi++)
#pragma unroll
    for (int r = 0; r < 4; r++) {
      int code = bn * 128 + wr * 64 + mi * 16 + l4 * 4 + r;
      cn[mi][r]  = cnorm[code];
      c2q[mi][r] = cs2[code];
    }

  float* rv = (float*)As;   // [2][128] per code-half
  int*   ri = (int*)Bs;
  __syncthreads();

#pragma unroll
  for (int ni = 0; ni < 4; ni++) {
    int token = bm * 128 + wc * 64 + ni * 16 + l15;
    float xsv = xs[token];          // coalesced across l15
    float best = 1e30f;
    int bi = 0;
#pragma unroll
    for (int mi = 0; mi < 4; mi++)
#pragma unroll
      for (int r = 0; r < 4; r++) {
        float v = fmaf(-xsv * c2q[mi][r], (float)acc[mi][ni][r], cn[mi][r]);
        int code = bn * 128 + wr * 64 + mi * 16 + l4 * 4 + r;
        if (v < best) { best = v; bi = code; }
      }
#pragma unroll
    for (int m = 16; m < 64; m <<= 1) {   // reduce over l4 groups
      float ov = __shfl_xor(best, m, 64);
      int   oi = __shfl_xor(bi, m, 64);
      if (ov < best) { best = ov; bi = oi; }
    }
    if (l4 == 0) {
      int tl = wc * 64 + ni * 16 + l15;   // 0..127 token within block
      rv[wr * 128 + tl] = best;
      ri[wr * 128 + tl] = bi;
    }
  }
  __syncthreads();
  if (tid < 128) {
    float bv = rv[tid];
    int   bb = ri[tid];
    float v1 = rv[128 + tid];
    if (v1 < bv) { bv = v1; bb = ri[128 + tid]; }
    size_t g = (size_t)bn * NTOK + bm * 128 + tid;
    pval[g] = bv;
    pidx[g] = bb;
  }
}

__global__ void argmin_reduce(const float* __restrict__ pval, const int* __restrict__ pidx,
                              int* __restrict__ idx) {
  int t = blockIdx.x * 256 + threadIdx.x;   // 0..32767
  float best = 1e30f;
  int bi = 0;
  for (int c = 0; c < 32; c++) {
    float v = pval[(size_t)c * NTOK + t];
    if (v < best) { best = v; bi = pidx[(size_t)c * NTOK + t]; }
  }
  idx[t] = bi;
}

// -------- gate GEMM (i8, R13-proven 2-buf form) + fused epilogue + loss ----
__global__ __launch_bounds__(512, 4)
void gate_i8(const u8* __restrict__ Xq, const u8* __restrict__ Wq,
             const float* __restrict__ X, const float* __restrict__ Cf,
             const float* __restrict__ gb, const float* __restrict__ xs,
             const float* __restrict__ ws, const int* __restrict__ idx,
             float* __restrict__ out, float* __restrict__ blockSum) {
  __shared__ __align__(16) u8 As[2][128 * 64];
  __shared__ __align__(16) u8 Bs[2][256 * 64];
  __shared__ float bsum[8];

  const int tid  = threadIdx.x;
  const int lane = tid & 63;
  const int wid  = tid >> 6;          // 0..7
  const int wr   = wid >> 2;          // 0..1
  const int wc   = wid & 3;           // 0..3
  const int bm   = blockIdx.x;        // 0..255 token tiles
  const int bn   = blockIdx.y;        // 0..1   col tiles (256 each)
  const int l15  = lane & 15, l4 = lane >> 4;

  const u8* Xg = Xq + (size_t)(bm * 128) * DIM;
  const u8* Wg = Wq + (size_t)(bn * 256) * DIM;

  auto stage = [&](int buf, int kt) {
    int kk = kt * 64;
    {
      int row = wid * 16 + (lane >> 2);
      gload_lds16(Xg + (size_t)row * DIM + kk + (lane & 3) * 16,
                  (void*)(As[buf] + wid * 1024));
    }
#pragma unroll
    for (int p = 0; p < 2; p++) {
      int row = p * 128 + wid * 16 + (lane >> 2);
      gload_lds16(Wg + (size_t)row * DIM + kk + (lane & 3) * 16,
                  (void*)(Bs[buf] + p * 8192 + wid * 1024));
    }
  };

  auto rd16 = [&](const u8* base, int row) -> i32x4 {
    return *reinterpret_cast<const i32x4*>(
        base + row * 64 + ((l4 ^ ((row >> 1) & 3)) << 4));
  };

  i32x4 acc[4][4];
#pragma unroll
  for (int i = 0; i < 4; i++)
#pragma unroll
    for (int j = 0; j < 4; j++)
#pragma unroll
      for (int r = 0; r < 4; r++) acc[i][j][r] = 0;

  stage(0, 0);
  stage(1, 1);
  asm volatile("s_waitcnt vmcnt(3)" ::: "memory");
  __builtin_amdgcn_s_barrier();
  asm volatile("" ::: "memory");

  for (int t = 0; t < 8; ++t) {
    const u8* A  = As[t & 1];
    const u8* Bt = Bs[t & 1];
    i32x4 bfr[4];
#pragma unroll
    for (int ni = 0; ni < 4; ni++) bfr[ni] = rd16(Bt, wc * 64 + ni * 16 + l15);
#pragma unroll
    for (int mi = 0; mi < 4; mi++) {
      i32x4 af = rd16(A, wr * 64 + mi * 16 + l15);
      __builtin_amdgcn_s_setprio(1);
#pragma unroll
      for (int ni = 0; ni < 4; ni++)
        acc[mi][ni] = __builtin_amdgcn_mfma_i32_16x16x64_i8(
            af, bfr[ni], acc[mi][ni], 0, 0, 0);
      __builtin_amdgcn_s_setprio(0);
    }

    asm volatile("" ::: "memory");
    __builtin_amdgcn_s_barrier();
    asm volatile("" ::: "memory");
    if (t + 2 < 8) {
      stage(t & 1, t + 2);
      asm volatile("s_waitcnt vmcnt(3)" ::: "memory");
      __builtin_amdgcn_s_barrier();
      asm volatile("" ::: "memory");
    } else if (t < 7) {
      asm volatile("s_waitcnt vmcnt(0)" ::: "memory");
      __builtin_amdgcn_s_barrier();
      asm volatile("" ::: "memory");
    }
  }

  // epilogue: gate = sigmoid(xs*ws*idot + b), out = x + c[idx]*gate, loss
  float wsv[4], gbv[4];
  int   cl[4];
#pragma unroll
  for (int ni = 0; ni < 4; ni++) {
    cl[ni] = bn * 256 + wc * 64 + ni * 16 + l15;
    wsv[ni] = ws[cl[ni]];
    gbv[ni] = gb[cl[ni]];
  }
  float lsum = 0.f;
#pragma unroll
  for (int mi = 0; mi < 4; mi++) {
#pragma unroll
    for (int r = 0; r < 4; r++) {
      int token = bm * 128 + wr * 64 + mi * 16 + l4 * 4 + r;
      int code = idx[token];
      float xsv = xs[token];
#pragma unroll
      for (int ni = 0; ni < 4; ni++) {
        int col = cl[ni];
        float logit = xsv * wsv[ni] * (float)acc[mi][ni][r] + gbv[ni];
        float g = 1.0f / (1.0f + __expf(-logit));
        float q = Cf[(size_t)code * DIM + col];
        float xx = X[(size_t)token * DIM + col];
        out[(size_t)token * DIM + col] = xx + q * g;
        float d = q - xx;
        lsum += d * d;
      }
    }
  }
#pragma unroll
  for (int m = 1; m < 64; m <<= 1) lsum += __shfl_xor(lsum, m, 64);
  if (lane == 0) bsum[wid] = lsum;
  __syncthreads();
  if (tid == 0) {
    float s = 0.f;
#pragma unroll
    for (int i = 0; i < 8; i++) s += bsum[i];
    blockSum[blockIdx.y * gridDim.x + blockIdx.x] = s;
  }
}

__global__ void finalize(const float* __restrict__ blockSum, float* __restrict__ out_loss) {
  int t = threadIdx.x;  // 256 threads, 512 partials
  float s = blockSum[t * 2] + blockSum[t * 2 + 1];
#pragma unroll
  for (int m = 1; m < 64; m <<= 1) s += __shfl_xor(s, m, 64);
  __shared__ float w4[4];
  if ((t & 63) == 0) w4[t >> 6] = s;
  __syncthreads();
  if (t == 0) {
    float tot = w4[0] + w4[1] + w4[2] + w4[3];
    out_loss[0] = 1.25f * tot / 16777216.0f;   // N*D = 32768*512
  }
}

extern "C" void kernel_launch(void* const* d_in, const int* in_sizes, int n_in,
                              void* d_out, int out_size, void* d_ws, size_t ws_size,
                              hipStream_t stream) {
  const float* X  = (const float*)d_in[0];   // [32768, 512]
  const float* CB = (const float*)d_in[1];   // [4096, 512]
  const float* GW = (const float*)d_in[2];   // [512, 512]
  const float* GB = (const float*)d_in[3];   // [512]
  float* out = (float*)d_out;                // [32768*512] output + [1] loss

  char* w = (char*)d_ws;
  size_t off = 0;
  auto alloc = [&](size_t bytes) -> void* {
    void* p = w + off;
    off = (off + bytes + 255) & ~(size_t)255;
    return p;
  };
  u8*    Xq    = (u8*) alloc((size_t)NTOK * DIM);       // 16.8 MB (i8, swizzled)
  u8*    Cq    = (u8*) alloc((size_t)KC * DIM);         // 2.1 MB
  u8*    Wq    = (u8*) alloc((size_t)DIM * DIM);        // 0.25 MB
  float* xsc   = (float*)alloc((size_t)NTOK * 4);       // per-token scale
  float* cnorm = (float*)alloc((size_t)KC * 4);
  float* cs2   = (float*)alloc((size_t)KC * 4);
  float* wsc   = (float*)alloc((size_t)DIM * 4);
  float* pval  = (float*)alloc((size_t)32 * NTOK * 4);  // 4.2 MB
  int*   pidx  = (int*)alloc((size_t)32 * NTOK * 4);    // 4.2 MB
  int*   idx   = (int*)alloc((size_t)NTOK * 4);
  float* bsums = (float*)alloc((size_t)512 * 4);

  cvt_x_i8<<<8192, 256, 0, stream>>>(X, Xq, xsc);
  cvt_cb_i8<<<1024, 256, 0, stream>>>(CB, Cq, cnorm, cs2);
  cvt_w_i8<<<128, 256, 0, stream>>>(GW, Wq, wsc);
  argmin_i8<<<dim3(256, 32), 256, 0, stream>>>(Xq, Cq, cnorm, cs2, xsc, pval, pidx);
  argmin_reduce<<<128, 256, 0, stream>>>(pval, pidx, idx);
  gate_i8<<<dim3(256, 2), 512, 0, stream>>>(Xq, Wq, X, CB, GB, xsc, wsc, idx, out, bsums);
  finalize<<<1, 256, 0, stream>>>(bsums, out + (size_t)NTOK * DIM);
}